// Round 4
// baseline (959.803 us; speedup 1.0000x reference)
//
#include <hip/hip_runtime.h>

typedef unsigned short ushort_t;
typedef unsigned int uint_t;

#define NN 20000
#define EE 320000
#define CC 32
#define NEL 10
#define GG 64
#define TTT 1000
#define NBB 8
#define HIDD 64
#define CHN 2000        // nodes per chunk (10 chunks)
#define CAP 48000       // max edges per chunk (expected ~32000, sigma ~170)

__device__ __forceinline__ float bits2f(uint_t b) { union { uint_t u; float f; } v; v.u = b; return v.f; }
__device__ __forceinline__ ushort_t f2b(float f) {
  union { float f; uint_t u; } v; v.f = f;
  uint_t r = (v.u + 0x7fffu + ((v.u >> 16) & 1u)) >> 16;
  return (ushort_t)r;
}
__device__ __forceinline__ uint_t pk(float a, float b) {
  return (uint_t)f2b(a) | ((uint_t)f2b(b) << 16);
}
__device__ __forceinline__ float lo16(uint_t u) { return bits2f(u << 16); }
__device__ __forceinline__ float hi16(uint_t u) { return bits2f(u & 0xffff0000u); }

// ---------------- K1: node prep (also zeroes deg) ----------------
__global__ __launch_bounds__(256) void k_prep(
    const float* __restrict__ positions, const float* __restrict__ node_attrs,
    const float* __restrict__ eps, const float* __restrict__ alpha_bar,
    const float* __restrict__ W_embed, const float* __restrict__ W_sc,
    const int* __restrict__ batch, const int* __restrict__ tarr,
    float* __restrict__ pos_noisy, float* __restrict__ scalA,
    float* __restrict__ sc_skip, float* __restrict__ pred, int* __restrict__ deg)
{
  int n = blockIdx.x * 256 + threadIdx.x;
  if (n >= NN) return;
  deg[n] = 0;
  int g = batch[n];
  int tn = tarr[g];
  float ab = alpha_bar[tn];
  float sa = sqrtf(ab), sb = sqrtf(fmaxf(1.0f - ab, 0.0f));
#pragma unroll
  for (int j = 0; j < 3; ++j)
    pos_noisy[n * 3 + j] = sa * positions[n * 3 + j] + sb * eps[n * 13 + 10 + j];
  float an[10];
#pragma unroll
  for (int j = 0; j < 10; ++j)
    an[j] = sa * 0.25f * node_attrs[n * 10 + j] + sb * eps[n * 13 + j];
  float tf = (float)tn * (1.0f / (float)TTT);
  for (int d = 0; d < CC; ++d) {
    float h = tf * W_embed[10 * CC + d];
    float sk = 0.0f;
#pragma unroll
    for (int j = 0; j < 10; ++j) {
      h = fmaf(an[j], W_embed[j * CC + d], h);
      sk = fmaf(an[j], W_sc[j * CC + d], sk);
    }
    scalA[n * CC + d] = h;
    sc_skip[n * CC + d] = sk;
  }
#pragma unroll
  for (int j = 0; j < 13; ++j) pred[n * 13 + j] = 0.0f;
}

// ---------------- K2a: receiver histogram ----------------
__global__ __launch_bounds__(256) void k_edge_deg(const int* __restrict__ ei,
    int* __restrict__ deg)
{
  int e = blockIdx.x * 256 + threadIdx.x;  // EE = 1250*256 exactly
  atomicAdd(&deg[ei[EE + e]], 1);
}

// ---------------- K3: exclusive scan deg -> offs, cursor; zero loss accum ----
__global__ __launch_bounds__(1024) void k_scan(const int* __restrict__ deg,
    int* __restrict__ offs, int* __restrict__ cursor,
    float* __restrict__ lnum, float* __restrict__ lcnt)
{
  __shared__ int wsums[16];
  __shared__ int woffs[16];
  int tid = threadIdx.x, lane = tid & 63, wv = tid >> 6;
  if (tid < GG) { lnum[tid] = 0.0f; lcnt[tid] = 0.0f; }
  int base = tid * 20;
  int loc[20];
  int s = 0;
#pragma unroll
  for (int j = 0; j < 20; ++j) {
    int idx = base + j;
    int v = (idx < NN) ? deg[idx] : 0;
    loc[j] = s; s += v;
  }
  int inc = s;
  for (int o = 1; o < 64; o <<= 1) {
    int v = __shfl_up(inc, o, 64);
    if (lane >= o) inc += v;
  }
  if (lane == 63) wsums[wv] = inc;
  __syncthreads();
  if (wv == 0 && lane < 16) {
    int v = wsums[lane];
    int i2 = v;
    for (int o = 1; o < 16; o <<= 1) {
      int vv = __shfl_up(i2, o, 16);
      if (lane >= o) i2 += vv;
    }
    woffs[lane] = i2 - v;
  }
  __syncthreads();
  int texcl = woffs[wv] + (inc - s);
#pragma unroll
  for (int j = 0; j < 20; ++j) {
    int idx = base + j;
    if (idx < NN) { int v = texcl + loc[j]; offs[idx] = v; cursor[idx] = v; }
  }
  if (tid == 1023) offs[NN] = EE;
}

// ---------------- K4: edge geometry, written into receiver-sorted slots ------
__global__ __launch_bounds__(256) void k_edge2(
    const float* __restrict__ pos_noisy, const float* __restrict__ shifts,
    const int* __restrict__ ei, int* __restrict__ cursor,
    ushort_t* __restrict__ Ys, ushort_t* __restrict__ efs, int* __restrict__ snds)
{
  int e = blockIdx.x * 256 + threadIdx.x;  // EE exact
  int snd = ei[e], rcv = ei[EE + e];
  float vx = pos_noisy[rcv * 3 + 0] - pos_noisy[snd * 3 + 0] + shifts[e * 3 + 0];
  float vy = pos_noisy[rcv * 3 + 1] - pos_noisy[snd * 3 + 1] + shifts[e * 3 + 1];
  float vz = pos_noisy[rcv * 3 + 2] - pos_noisy[snd * 3 + 2] + shifts[e * 3 + 2];
  float r2 = vx * vx + vy * vy + vz * vz + 1e-12f;
  float r = sqrtf(r2);
  float inv = 1.0f / r;
  float x = vx * inv, y = vy * inv, z = vz * inv;

  const float s3 = 1.7320508075688772f, s15 = 3.872983346207417f, s5 = 2.23606797749979f;
  const float s105 = 10.246950765959598f, s7 = 2.6457513110645907f;
  const float s35_8 = 2.091650066335189f, s21_8 = 1.6201851746019651f;
  float yv[16];
  yv[0] = 1.0f;
  yv[1] = s3 * x; yv[2] = s3 * y; yv[3] = s3 * z;
  yv[4] = s15 * x * y;
  yv[5] = s15 * y * z;
  yv[6] = 0.5f * s5 * (3.0f * z * z - 1.0f);
  yv[7] = s15 * x * z;
  yv[8] = 0.5f * s15 * (x * x - y * y);
  yv[9] = s35_8 * y * (3.0f * x * x - y * y);
  yv[10] = s105 * x * y * z;
  yv[11] = s21_8 * y * (5.0f * z * z - 1.0f);
  yv[12] = 0.5f * s7 * (5.0f * z * z * z - 3.0f * z);
  yv[13] = s21_8 * x * (5.0f * z * z - 1.0f);
  yv[14] = 0.5f * s105 * z * (x * x - y * y);
  yv[15] = s35_8 * x * (x * x - 3.0f * y * y);

  // radial embed: sqrt(2/5) * sin(n*pi*rc/5)/rc * poly_cutoff(r/5)
  float rc = fmaxf(r, 1e-9f);
  float pref = 0.6324555320336759f / rc;
  float th = 0.6283185307179586f * rc;
  float s1 = __sinf(th), c1 = __cosf(th);
  float xr = r * 0.2f;
  float fcut = 0.0f;
  if (xr < 1.0f) {
    float x2 = xr * xr, x3 = x2 * xr;
    float x6 = x3 * x3, x7 = x6 * xr, x8 = x7 * xr;
    fcut = 1.0f - 28.0f * x6 + 48.0f * x7 - 21.0f * x8;
  }
  float efv[8];
  float sp = 0.0f, scur = s1, c2 = 2.0f * c1;
#pragma unroll
  for (int b = 0; b < 8; ++b) {
    efv[b] = pref * scur * fcut;
    float nx = c2 * scur - sp;   // sin((n+1)th) = 2cos(th)sin(n th) - sin((n-1)th)
    sp = scur; scur = nx;
  }

  int slot = atomicAdd(&cursor[rcv], 1);
  snds[slot] = snd;
  uint4* Y4 = (uint4*)Ys;
  Y4[(size_t)slot * 2 + 0] = make_uint4(pk(yv[0], yv[1]), pk(yv[2], yv[3]),
                                        pk(yv[4], yv[5]), pk(yv[6], yv[7]));
  Y4[(size_t)slot * 2 + 1] = make_uint4(pk(yv[8], yv[9]), pk(yv[10], yv[11]),
                                        pk(yv[12], yv[13]), pk(yv[14], yv[15]));
  ((uint4*)efs)[slot] = make_uint4(pk(efv[0], efv[1]), pk(efv[2], efv[3]),
                                   pk(efv[4], efv[5]), pk(efv[6], efv[7]));
}

// ---------------- K5: radial MLP for one chunk's sorted edge range ------------
__global__ __launch_bounds__(256) void k_rw(
    const ushort_t* __restrict__ efs, const float* __restrict__ W_r1,
    const float* __restrict__ W_r2, ushort_t* __restrict__ rwc,
    const int* __restrict__ offs, int layer, int n0, int n1)
{
  int base = offs[n0];
  int nE = offs[n1] - base;
  if (nE > CAP) nE = CAP;           // memory-safety clamp (never hit in practice)
  int tile = blockIdx.x * 64;
  if (tile >= nE) return;           // uniform early-exit

  __shared__ __align__(16) float w1s[NBB * HIDD];
  __shared__ __align__(16) float w2s[HIDD * 128];
  __shared__ __align__(16) float h1t[HIDD][72];
  int tid = threadIdx.x;
  const float* W1g = W_r1 + layer * NBB * HIDD;
  const float* W2g = W_r2 + layer * HIDD * 128;
  for (int i = tid; i < NBB * HIDD; i += 256) w1s[i] = W1g[i];
  for (int i = tid; i < HIDD * 128; i += 256) w2s[i] = W2g[i];
  __syncthreads();
  {
    int le = tid & 63, hb = (tid >> 6) * 16;
    bool ok = (tile + le) < nE;
    float efr[8] = {0, 0, 0, 0, 0, 0, 0, 0};
    if (ok) {
      uint4 q = ((const uint4*)efs)[(size_t)(base + tile + le)];
      efr[0] = lo16(q.x); efr[1] = hi16(q.x);
      efr[2] = lo16(q.y); efr[3] = hi16(q.y);
      efr[4] = lo16(q.z); efr[5] = hi16(q.z);
      efr[6] = lo16(q.w); efr[7] = hi16(q.w);
    }
    for (int hh = 0; hh < 16; ++hh) {
      int h = hb + hh;
      float t = 0.0f;
#pragma unroll
      for (int b = 0; b < 8; ++b) t = fmaf(efr[b], w1s[b * HIDD + h], t);
      float sg = 1.0f / (1.0f + __expf(-t));
      h1t[h][le] = ok ? (t * sg) : 0.0f;
    }
  }
  __syncthreads();
  int eg = tid & 7, jg = tid >> 3;
  float acc[8][4];
#pragma unroll
  for (int i = 0; i < 8; ++i) { acc[i][0] = 0; acc[i][1] = 0; acc[i][2] = 0; acc[i][3] = 0; }
#pragma unroll 8
  for (int h = 0; h < HIDD; ++h) {
    float4 wv = *(const float4*)(&w2s[h * 128 + jg * 4]);
    float4 xa = *(const float4*)(&h1t[h][eg * 8]);
    float4 xb = *(const float4*)(&h1t[h][eg * 8 + 4]);
    float xs[8] = {xa.x, xa.y, xa.z, xa.w, xb.x, xb.y, xb.z, xb.w};
    float wvv[4] = {wv.x, wv.y, wv.z, wv.w};
#pragma unroll
    for (int i = 0; i < 8; ++i)
#pragma unroll
      for (int j = 0; j < 4; ++j)
        acc[i][j] = fmaf(xs[i], wvv[j], acc[i][j]);
  }
  uint2* rw2 = (uint2*)rwc;
#pragma unroll
  for (int i = 0; i < 8; ++i) {
    int li = tile + eg * 8 + i;
    if (li < nE) {
      uint_t lo = pk(acc[i][0], acc[i][1]);
      uint_t hi = pk(acc[i][2], acc[i][3]);
      rw2[(size_t)li * 32 + jg] = make_uint2(lo, hi);
    }
  }
}

// ---------------- K6: fused aggregate + mix + poly + readout (per chunk) ------
__global__ __launch_bounds__(256) void k_layer(
    const ushort_t* __restrict__ Ys, const ushort_t* __restrict__ rwc,
    const int* __restrict__ snds,
    const float* __restrict__ scal_in, float* __restrict__ scal_out,
    const int* __restrict__ offs,
    const float* __restrict__ W_mix, const float* __restrict__ W_prod,
    const float* __restrict__ W_ro_s, const float* __restrict__ W_ro_v,
    const float* __restrict__ sc_skip, float* __restrict__ pred, int layer, int n0)
{
  __shared__ float lagg[4][CC][16];
  __shared__ float lf[4][CC][4];
  int w = threadIdx.x >> 6, lane = threadIdx.x & 63;
  int n = n0 + blockIdx.x * 4 + w;   // CHN = 500*4 exactly
  int c = lane >> 1;
  int kh = lane & 1;
  int kb = kh * 8;
  int base = offs[n0];
  int i0 = offs[n], i1 = offs[n + 1];
  if (i1 - base > CAP) i1 = base + CAP;   // match k_rw clamp (never hit)
  float acc0 = 0, acc1 = 0, acc2 = 0, acc3 = 0, acc4 = 0, acc5 = 0, acc6 = 0, acc7 = 0;
  const uint4* Y4 = (const uint4*)Ys;
  const uint2* rw2 = (const uint2*)rwc;
  for (int s = i0; s < i1; ++s) {
    uint4 q = Y4[(size_t)s * 2 + kh];
    uint2 rp = rw2[(size_t)(s - base) * 32 + c];
    float ss = scal_in[snds[s] * CC + c];
    float r0 = lo16(rp.x), r1 = hi16(rp.x), r2v = lo16(rp.y), r3 = hi16(rp.y);
    // L_OF_LM: kh0 -> l={0,1,1,1,2,2,2,2}; kh1 -> l={2,3,3,3,3,3,3,3}
    float w0 = kh ? r2v : r0;
    float w13 = kh ? r3 : r1;
    float w47 = kh ? r3 : r2v;
    float ya0 = lo16(q.x), ya1 = hi16(q.x), ya2 = lo16(q.y), ya3 = hi16(q.y);
    float yb0 = lo16(q.z), yb1 = hi16(q.z), yb2 = lo16(q.w), yb3 = hi16(q.w);
    acc0 = fmaf(w0 * ss, ya0, acc0);
    acc1 = fmaf(w13 * ss, ya1, acc1);
    acc2 = fmaf(w13 * ss, ya2, acc2);
    acc3 = fmaf(w13 * ss, ya3, acc3);
    acc4 = fmaf(w47 * ss, yb0, acc4);
    acc5 = fmaf(w47 * ss, yb1, acc5);
    acc6 = fmaf(w47 * ss, yb2, acc6);
    acc7 = fmaf(w47 * ss, yb3, acc7);
  }
  const float invavg = 1.0f / 16.0f;
  lagg[w][c][kb + 0] = acc0 * invavg;
  lagg[w][c][kb + 1] = acc1 * invavg;
  lagg[w][c][kb + 2] = acc2 * invavg;
  lagg[w][c][kb + 3] = acc3 * invavg;
  lagg[w][c][kb + 4] = acc4 * invavg;
  lagg[w][c][kb + 5] = acc5 * invavg;
  lagg[w][c][kb + 6] = acc6 * invavg;
  lagg[w][c][kb + 7] = acc7 * invavg;
  __syncthreads();
  int d = c;
  float ft[8] = {0, 0, 0, 0, 0, 0, 0, 0};
  const float* Wm = W_mix + layer * 4096;
  for (int cc2 = 0; cc2 < CC; ++cc2) {
    float m0 = Wm[cc2 * CC + d];
    float m1 = Wm[1024 + cc2 * CC + d];
    float m2 = Wm[2048 + cc2 * CC + d];
    float m3 = Wm[3072 + cc2 * CC + d];
    float u0 = kh ? m2 : m0;
    float u13 = kh ? m3 : m1;
    float u47 = kh ? m3 : m2;
    ft[0] = fmaf(lagg[w][cc2][kb + 0], u0, ft[0]);
    ft[1] = fmaf(lagg[w][cc2][kb + 1], u13, ft[1]);
    ft[2] = fmaf(lagg[w][cc2][kb + 2], u13, ft[2]);
    ft[3] = fmaf(lagg[w][cc2][kb + 3], u13, ft[3]);
    ft[4] = fmaf(lagg[w][cc2][kb + 4], u47, ft[4]);
    ft[5] = fmaf(lagg[w][cc2][kb + 5], u47, ft[5]);
    ft[6] = fmaf(lagg[w][cc2][kb + 6], u47, ft[6]);
    ft[7] = fmaf(lagg[w][cc2][kb + 7], u47, ft[7]);
  }
  float s = __shfl(ft[0], lane & 62, 64);   // k=0 (pre-poly) from even lane of pair
  const float* Wp = W_prod + layer * 96;
  float p0 = Wp[d], p1 = Wp[32 + d], p2 = Wp[64 + d];
  float poly = fmaf(fmaf(p2, s, p1), s, p0);
#pragma unroll
  for (int j = 0; j < 8; ++j) ft[j] *= poly;
  if (layer == 0 && kh == 0) ft[0] += sc_skip[n * CC + d];
  if (kh == 0) {
    scal_out[n * CC + d] = ft[0];
    lf[w][d][0] = ft[0]; lf[w][d][1] = ft[1]; lf[w][d][2] = ft[2]; lf[w][d][3] = ft[3];
  }
  __syncthreads();
  if (lane < 13) {
    float sum = 0.0f;
    if (lane < 10) {
      const float* Wr = W_ro_s + layer * CC * NEL;
      for (int dd = 0; dd < CC; ++dd) sum = fmaf(lf[w][dd][0], Wr[dd * NEL + lane], sum);
    } else {
      int mm = lane - 10;
      const float* Wv = W_ro_v + layer * CC;
      for (int dd = 0; dd < CC; ++dd) sum = fmaf(lf[w][dd][1 + mm], Wv[dd], sum);
    }
    pred[n * 13 + lane] += sum;
  }
}

// ---------------- K7: loss accumulation ----------------
__global__ __launch_bounds__(256) void k_loss(const float* __restrict__ pred,
    const float* __restrict__ eps, const int* __restrict__ batch,
    float* __restrict__ lnum, float* __restrict__ lcnt)
{
  int n = blockIdx.x * 256 + threadIdx.x;
  if (n >= NN) return;
  int g = batch[n];
  float sum = 0.0f;
#pragma unroll
  for (int j = 0; j < 13; ++j) {
    float dlt = pred[n * 13 + j] - eps[n * 13 + j];
    sum = fmaf(dlt, dlt, sum);
  }
  atomicAdd(&lnum[g], sum);
  atomicAdd(&lcnt[g], 1.0f);
}

__global__ void k_final(const float* __restrict__ lnum, const float* __restrict__ lcnt,
    float* __restrict__ out)
{
  int g = threadIdx.x;
  if (g < GG) {
    float nn = fmaxf(lcnt[g], 1.0f);
    out[g] = 0.5f * lnum[g] / (nn * 13.0f);
  }
}

extern "C" void kernel_launch(void* const* d_in, const int* in_sizes, int n_in,
                              void* d_out, int out_size, void* d_ws, size_t ws_size,
                              hipStream_t stream) {
  const float* positions  = (const float*)d_in[0];
  const float* node_attrs = (const float*)d_in[1];
  const float* shifts     = (const float*)d_in[2];
  const float* eps        = (const float*)d_in[3];
  const float* alpha_bar  = (const float*)d_in[4];
  const float* W_embed    = (const float*)d_in[5];
  const float* W_r1       = (const float*)d_in[6];
  const float* W_r2       = (const float*)d_in[7];
  const float* W_mix      = (const float*)d_in[8];
  const float* W_sc       = (const float*)d_in[9];
  const float* W_prod     = (const float*)d_in[10];
  const float* W_ro_s     = (const float*)d_in[11];
  const float* W_ro_v     = (const float*)d_in[12];
  const int* edge_index   = (const int*)d_in[13];
  const int* batch        = (const int*)d_in[14];
  const int* tarr         = (const int*)d_in[15];
  float* out = (float*)d_out;

  char* ws = (char*)d_ws;
  size_t off = 0;
  auto alloc = [&](size_t bytes) -> void* {
    void* p = ws + off;
    off = (off + bytes + 255) & ~(size_t)255;
    return p;
  };
  // total ~38 MB
  float* pos_noisy = (float*)alloc(NN * 3 * 4);
  float* scalA     = (float*)alloc(NN * CC * 4);
  float* scalB     = (float*)alloc(NN * CC * 4);
  float* sc_skip   = (float*)alloc(NN * CC * 4);
  float* pred      = (float*)alloc(NN * 13 * 4);
  ushort_t* Ys     = (ushort_t*)alloc((size_t)EE * 16 * 2);  // sorted, bf16
  ushort_t* efs    = (ushort_t*)alloc((size_t)EE * 8 * 2);   // sorted, bf16
  int* snds        = (int*)alloc((size_t)EE * 4);            // sorted sender ids
  ushort_t* rwc    = (ushort_t*)alloc((size_t)CAP * 128 * 2);// chunk rw, bf16
  int* deg         = (int*)alloc(NN * 4);
  int* offs        = (int*)alloc((NN + 1) * 4);
  int* cursor      = (int*)alloc(NN * 4);
  float* lnum      = (float*)alloc(GG * 4);
  float* lcnt      = (float*)alloc(GG * 4);
  (void)ws_size; (void)in_sizes; (void)n_in; (void)out_size;

  const int NB_N = (NN + 255) / 256;   // 79
  const int NB_E = EE / 256;           // 1250

  k_prep<<<NB_N, 256, 0, stream>>>(positions, node_attrs, eps, alpha_bar, W_embed,
                                   W_sc, batch, tarr, pos_noisy, scalA, sc_skip, pred, deg);
  k_edge_deg<<<NB_E, 256, 0, stream>>>(edge_index, deg);
  k_scan<<<1, 1024, 0, stream>>>(deg, offs, cursor, lnum, lcnt);
  k_edge2<<<NB_E, 256, 0, stream>>>(pos_noisy, shifts, edge_index, cursor, Ys, efs, snds);

  for (int layer = 0; layer < 2; ++layer) {
    const float* sin_p = (layer == 0) ? scalA : scalB;
    float* sout_p      = (layer == 0) ? scalB : scalA;
    for (int ch = 0; ch < NN / CHN; ++ch) {
      int n0 = ch * CHN, n1 = n0 + CHN;
      k_rw<<<CAP / 64, 256, 0, stream>>>(efs, W_r1, W_r2, rwc, offs, layer, n0, n1);
      k_layer<<<CHN / 4, 256, 0, stream>>>(Ys, rwc, snds, sin_p, sout_p, offs,
                                           W_mix, W_prod, W_ro_s, W_ro_v,
                                           sc_skip, pred, layer, n0);
    }
  }

  k_loss<<<NB_N, 256, 0, stream>>>(pred, eps, batch, lnum, lcnt);
  k_final<<<1, 64, 0, stream>>>(lnum, lcnt, out);
}

// Round 5
// 624.793 us; speedup vs baseline: 1.5362x; 1.5362x over previous
//
#include <hip/hip_runtime.h>

typedef unsigned short ushort_t;
typedef unsigned int uint_t;

#define NN 20000
#define EE 320000
#define CC 32
#define NEL 10
#define GG 64
#define TTT 1000
#define NBB 8
#define HIDD 64
#define CHN 4000        // nodes per chunk (5 chunks)
#define CAP 80000       // max edges per chunk (expected ~64000, sigma ~226; +70σ)

__device__ __forceinline__ float bits2f(uint_t b) { union { uint_t u; float f; } v; v.u = b; return v.f; }
__device__ __forceinline__ ushort_t f2b(float f) {
  union { float f; uint_t u; } v; v.f = f;
  uint_t r = (v.u + 0x7fffu + ((v.u >> 16) & 1u)) >> 16;
  return (ushort_t)r;
}
__device__ __forceinline__ uint_t pk(float a, float b) {
  return (uint_t)f2b(a) | ((uint_t)f2b(b) << 16);
}
__device__ __forceinline__ float lo16(uint_t u) { return bits2f(u << 16); }
__device__ __forceinline__ float hi16(uint_t u) { return bits2f(u & 0xffff0000u); }

// ---------------- K1: node prep (also zeroes deg) ----------------
__global__ __launch_bounds__(256) void k_prep(
    const float* __restrict__ positions, const float* __restrict__ node_attrs,
    const float* __restrict__ eps, const float* __restrict__ alpha_bar,
    const float* __restrict__ W_embed, const float* __restrict__ W_sc,
    const int* __restrict__ batch, const int* __restrict__ tarr,
    float* __restrict__ pos_noisy, float* __restrict__ scalA,
    float* __restrict__ sc_skip, float* __restrict__ pred, int* __restrict__ deg)
{
  int n = blockIdx.x * 256 + threadIdx.x;
  if (n >= NN) return;
  deg[n] = 0;
  int g = batch[n];
  int tn = tarr[g];
  float ab = alpha_bar[tn];
  float sa = sqrtf(ab), sb = sqrtf(fmaxf(1.0f - ab, 0.0f));
#pragma unroll
  for (int j = 0; j < 3; ++j)
    pos_noisy[n * 3 + j] = sa * positions[n * 3 + j] + sb * eps[n * 13 + 10 + j];
  float an[10];
#pragma unroll
  for (int j = 0; j < 10; ++j)
    an[j] = sa * 0.25f * node_attrs[n * 10 + j] + sb * eps[n * 13 + j];
  float tf = (float)tn * (1.0f / (float)TTT);
  for (int d = 0; d < CC; ++d) {
    float h = tf * W_embed[10 * CC + d];
    float sk = 0.0f;
#pragma unroll
    for (int j = 0; j < 10; ++j) {
      h = fmaf(an[j], W_embed[j * CC + d], h);
      sk = fmaf(an[j], W_sc[j * CC + d], sk);
    }
    scalA[n * CC + d] = h;
    sc_skip[n * CC + d] = sk;
  }
#pragma unroll
  for (int j = 0; j < 13; ++j) pred[n * 13 + j] = 0.0f;
}

// ---------------- K2a: receiver histogram ----------------
__global__ __launch_bounds__(256) void k_edge_deg(const int* __restrict__ ei,
    int* __restrict__ deg)
{
  int e = blockIdx.x * 256 + threadIdx.x;  // EE = 1250*256 exactly
  atomicAdd(&deg[ei[EE + e]], 1);
}

// ---------------- K3: exclusive scan deg -> offs, cursor; zero loss accum ----
__global__ __launch_bounds__(1024) void k_scan(const int* __restrict__ deg,
    int* __restrict__ offs, int* __restrict__ cursor,
    float* __restrict__ lnum, float* __restrict__ lcnt)
{
  __shared__ int wsums[16];
  __shared__ int woffs[16];
  int tid = threadIdx.x, lane = tid & 63, wv = tid >> 6;
  if (tid < GG) { lnum[tid] = 0.0f; lcnt[tid] = 0.0f; }
  int base = tid * 20;
  int loc[20];
  int s = 0;
#pragma unroll
  for (int j = 0; j < 20; ++j) {
    int idx = base + j;
    int v = (idx < NN) ? deg[idx] : 0;
    loc[j] = s; s += v;
  }
  int inc = s;
  for (int o = 1; o < 64; o <<= 1) {
    int v = __shfl_up(inc, o, 64);
    if (lane >= o) inc += v;
  }
  if (lane == 63) wsums[wv] = inc;
  __syncthreads();
  if (wv == 0 && lane < 16) {
    int v = wsums[lane];
    int i2 = v;
    for (int o = 1; o < 16; o <<= 1) {
      int vv = __shfl_up(i2, o, 16);
      if (lane >= o) i2 += vv;
    }
    woffs[lane] = i2 - v;
  }
  __syncthreads();
  int texcl = woffs[wv] + (inc - s);
#pragma unroll
  for (int j = 0; j < 20; ++j) {
    int idx = base + j;
    if (idx < NN) { int v = texcl + loc[j]; offs[idx] = v; cursor[idx] = v; }
  }
  if (tid == 1023) offs[NN] = EE;
}

// ---------------- K4: edge geometry, written into receiver-sorted slots ------
__global__ __launch_bounds__(256) void k_edge2(
    const float* __restrict__ pos_noisy, const float* __restrict__ shifts,
    const int* __restrict__ ei, int* __restrict__ cursor,
    ushort_t* __restrict__ Ys, ushort_t* __restrict__ efs, int* __restrict__ snds)
{
  int e = blockIdx.x * 256 + threadIdx.x;  // EE exact
  int snd = ei[e], rcv = ei[EE + e];
  float vx = pos_noisy[rcv * 3 + 0] - pos_noisy[snd * 3 + 0] + shifts[e * 3 + 0];
  float vy = pos_noisy[rcv * 3 + 1] - pos_noisy[snd * 3 + 1] + shifts[e * 3 + 1];
  float vz = pos_noisy[rcv * 3 + 2] - pos_noisy[snd * 3 + 2] + shifts[e * 3 + 2];
  float r2 = vx * vx + vy * vy + vz * vz + 1e-12f;
  float r = sqrtf(r2);
  float inv = 1.0f / r;
  float x = vx * inv, y = vy * inv, z = vz * inv;

  const float s3 = 1.7320508075688772f, s15 = 3.872983346207417f, s5 = 2.23606797749979f;
  const float s105 = 10.246950765959598f, s7 = 2.6457513110645907f;
  const float s35_8 = 2.091650066335189f, s21_8 = 1.6201851746019651f;
  float yv[16];
  yv[0] = 1.0f;
  yv[1] = s3 * x; yv[2] = s3 * y; yv[3] = s3 * z;
  yv[4] = s15 * x * y;
  yv[5] = s15 * y * z;
  yv[6] = 0.5f * s5 * (3.0f * z * z - 1.0f);
  yv[7] = s15 * x * z;
  yv[8] = 0.5f * s15 * (x * x - y * y);
  yv[9] = s35_8 * y * (3.0f * x * x - y * y);
  yv[10] = s105 * x * y * z;
  yv[11] = s21_8 * y * (5.0f * z * z - 1.0f);
  yv[12] = 0.5f * s7 * (5.0f * z * z * z - 3.0f * z);
  yv[13] = s21_8 * x * (5.0f * z * z - 1.0f);
  yv[14] = 0.5f * s105 * z * (x * x - y * y);
  yv[15] = s35_8 * x * (x * x - 3.0f * y * y);

  // radial embed: sqrt(2/5) * sin(n*pi*rc/5)/rc * poly_cutoff(r/5)
  float rc = fmaxf(r, 1e-9f);
  float pref = 0.6324555320336759f / rc;
  float th = 0.6283185307179586f * rc;
  float s1 = __sinf(th), c1 = __cosf(th);
  float xr = r * 0.2f;
  float fcut = 0.0f;
  if (xr < 1.0f) {
    float x2 = xr * xr, x3 = x2 * xr;
    float x6 = x3 * x3, x7 = x6 * xr, x8 = x7 * xr;
    fcut = 1.0f - 28.0f * x6 + 48.0f * x7 - 21.0f * x8;
  }
  float efv[8];
  float sp = 0.0f, scur = s1, c2 = 2.0f * c1;
#pragma unroll
  for (int b = 0; b < 8; ++b) {
    efv[b] = pref * scur * fcut;
    float nx = c2 * scur - sp;   // sin((n+1)th) = 2cos(th)sin(n th) - sin((n-1)th)
    sp = scur; scur = nx;
  }

  int slot = atomicAdd(&cursor[rcv], 1);
  snds[slot] = snd;
  uint4* Y4 = (uint4*)Ys;
  Y4[(size_t)slot * 2 + 0] = make_uint4(pk(yv[0], yv[1]), pk(yv[2], yv[3]),
                                        pk(yv[4], yv[5]), pk(yv[6], yv[7]));
  Y4[(size_t)slot * 2 + 1] = make_uint4(pk(yv[8], yv[9]), pk(yv[10], yv[11]),
                                        pk(yv[12], yv[13]), pk(yv[14], yv[15]));
  ((uint4*)efs)[slot] = make_uint4(pk(efv[0], efv[1]), pk(efv[2], efv[3]),
                                   pk(efv[4], efv[5]), pk(efv[6], efv[7]));
}

// ---------------- K5: radial MLP for one chunk's sorted edge range ------------
__global__ __launch_bounds__(256) void k_rw(
    const ushort_t* __restrict__ efs, const float* __restrict__ W_r1,
    const float* __restrict__ W_r2, ushort_t* __restrict__ rwc,
    const int* __restrict__ offs, int layer, int n0, int n1)
{
  int base = offs[n0];
  int nE = offs[n1] - base;
  if (nE > CAP) nE = CAP;           // memory-safety clamp (never hit in practice)
  int tile = blockIdx.x * 64;
  if (tile >= nE) return;           // uniform early-exit

  __shared__ __align__(16) float w1s[NBB * HIDD];
  __shared__ __align__(16) float w2s[HIDD * 128];
  __shared__ __align__(16) float h1t[HIDD][72];
  int tid = threadIdx.x;
  const float* W1g = W_r1 + layer * NBB * HIDD;
  const float* W2g = W_r2 + layer * HIDD * 128;
  for (int i = tid; i < NBB * HIDD; i += 256) w1s[i] = W1g[i];
  for (int i = tid; i < HIDD * 128; i += 256) w2s[i] = W2g[i];
  __syncthreads();
  {
    int le = tid & 63, hb = (tid >> 6) * 16;
    bool ok = (tile + le) < nE;
    float efr[8] = {0, 0, 0, 0, 0, 0, 0, 0};
    if (ok) {
      uint4 q = ((const uint4*)efs)[(size_t)(base + tile + le)];
      efr[0] = lo16(q.x); efr[1] = hi16(q.x);
      efr[2] = lo16(q.y); efr[3] = hi16(q.y);
      efr[4] = lo16(q.z); efr[5] = hi16(q.z);
      efr[6] = lo16(q.w); efr[7] = hi16(q.w);
    }
    for (int hh = 0; hh < 16; ++hh) {
      int h = hb + hh;
      float t = 0.0f;
#pragma unroll
      for (int b = 0; b < 8; ++b) t = fmaf(efr[b], w1s[b * HIDD + h], t);
      float sg = 1.0f / (1.0f + __expf(-t));
      h1t[h][le] = ok ? (t * sg) : 0.0f;
    }
  }
  __syncthreads();
  int eg = tid & 7, jg = tid >> 3;
  float acc[8][4];
#pragma unroll
  for (int i = 0; i < 8; ++i) { acc[i][0] = 0; acc[i][1] = 0; acc[i][2] = 0; acc[i][3] = 0; }
#pragma unroll 8
  for (int h = 0; h < HIDD; ++h) {
    float4 wv = *(const float4*)(&w2s[h * 128 + jg * 4]);
    float4 xa = *(const float4*)(&h1t[h][eg * 8]);
    float4 xb = *(const float4*)(&h1t[h][eg * 8 + 4]);
    float xs[8] = {xa.x, xa.y, xa.z, xa.w, xb.x, xb.y, xb.z, xb.w};
    float wvv[4] = {wv.x, wv.y, wv.z, wv.w};
#pragma unroll
    for (int i = 0; i < 8; ++i)
#pragma unroll
      for (int j = 0; j < 4; ++j)
        acc[i][j] = fmaf(xs[i], wvv[j], acc[i][j]);
  }
  uint2* rw2 = (uint2*)rwc;
#pragma unroll
  for (int i = 0; i < 8; ++i) {
    int li = tile + eg * 8 + i;
    if (li < nE) {
      uint_t lo = pk(acc[i][0], acc[i][1]);
      uint_t hi = pk(acc[i][2], acc[i][3]);
      rw2[(size_t)li * 32 + jg] = make_uint2(lo, hi);
    }
  }
}

// ---------------- K6: fused aggregate + mix + poly + readout (per chunk) ------
__global__ __launch_bounds__(256) void k_layer(
    const ushort_t* __restrict__ Ys, const ushort_t* __restrict__ rwc,
    const int* __restrict__ snds,
    const float* __restrict__ scal_in, float* __restrict__ scal_out,
    const int* __restrict__ offs,
    const float* __restrict__ W_mix, const float* __restrict__ W_prod,
    const float* __restrict__ W_ro_s, const float* __restrict__ W_ro_v,
    const float* __restrict__ sc_skip, float* __restrict__ pred, int layer, int n0)
{
  __shared__ float lagg[4][CC][16];
  __shared__ float lf[4][CC][4];
  int w = threadIdx.x >> 6, lane = threadIdx.x & 63;
  int n = n0 + blockIdx.x * 4 + w;   // CHN = 1000*4 exactly
  int c = lane >> 1;
  int kh = lane & 1;
  int kb = kh * 8;
  int base = offs[n0];
  int i0 = offs[n], i1 = offs[n + 1];
  if (i1 - base > CAP) i1 = base + CAP;   // match k_rw clamp (never hit)
  float acc0 = 0, acc1 = 0, acc2 = 0, acc3 = 0, acc4 = 0, acc5 = 0, acc6 = 0, acc7 = 0;
  const uint4* Y4 = (const uint4*)Ys;
  const uint2* rw2 = (const uint2*)rwc;
  for (int s = i0; s < i1; ++s) {
    uint4 q = Y4[(size_t)s * 2 + kh];
    uint2 rp = rw2[(size_t)(s - base) * 32 + c];
    float ss = scal_in[snds[s] * CC + c];
    float r0 = lo16(rp.x), r1 = hi16(rp.x), r2v = lo16(rp.y), r3 = hi16(rp.y);
    // L_OF_LM: kh0 -> l={0,1,1,1,2,2,2,2}; kh1 -> l={2,3,3,3,3,3,3,3}
    float w0 = kh ? r2v : r0;
    float w13 = kh ? r3 : r1;
    float w47 = kh ? r3 : r2v;
    float ya0 = lo16(q.x), ya1 = hi16(q.x), ya2 = lo16(q.y), ya3 = hi16(q.y);
    float yb0 = lo16(q.z), yb1 = hi16(q.z), yb2 = lo16(q.w), yb3 = hi16(q.w);
    acc0 = fmaf(w0 * ss, ya0, acc0);
    acc1 = fmaf(w13 * ss, ya1, acc1);
    acc2 = fmaf(w13 * ss, ya2, acc2);
    acc3 = fmaf(w13 * ss, ya3, acc3);
    acc4 = fmaf(w47 * ss, yb0, acc4);
    acc5 = fmaf(w47 * ss, yb1, acc5);
    acc6 = fmaf(w47 * ss, yb2, acc6);
    acc7 = fmaf(w47 * ss, yb3, acc7);
  }
  const float invavg = 1.0f / 16.0f;
  lagg[w][c][kb + 0] = acc0 * invavg;
  lagg[w][c][kb + 1] = acc1 * invavg;
  lagg[w][c][kb + 2] = acc2 * invavg;
  lagg[w][c][kb + 3] = acc3 * invavg;
  lagg[w][c][kb + 4] = acc4 * invavg;
  lagg[w][c][kb + 5] = acc5 * invavg;
  lagg[w][c][kb + 6] = acc6 * invavg;
  lagg[w][c][kb + 7] = acc7 * invavg;
  __syncthreads();
  int d = c;
  float ft[8] = {0, 0, 0, 0, 0, 0, 0, 0};
  const float* Wm = W_mix + layer * 4096;
  for (int cc2 = 0; cc2 < CC; ++cc2) {
    float m0 = Wm[cc2 * CC + d];
    float m1 = Wm[1024 + cc2 * CC + d];
    float m2 = Wm[2048 + cc2 * CC + d];
    float m3 = Wm[3072 + cc2 * CC + d];
    float u0 = kh ? m2 : m0;
    float u13 = kh ? m3 : m1;
    float u47 = kh ? m3 : m2;
    ft[0] = fmaf(lagg[w][cc2][kb + 0], u0, ft[0]);
    ft[1] = fmaf(lagg[w][cc2][kb + 1], u13, ft[1]);
    ft[2] = fmaf(lagg[w][cc2][kb + 2], u13, ft[2]);
    ft[3] = fmaf(lagg[w][cc2][kb + 3], u13, ft[3]);
    ft[4] = fmaf(lagg[w][cc2][kb + 4], u47, ft[4]);
    ft[5] = fmaf(lagg[w][cc2][kb + 5], u47, ft[5]);
    ft[6] = fmaf(lagg[w][cc2][kb + 6], u47, ft[6]);
    ft[7] = fmaf(lagg[w][cc2][kb + 7], u47, ft[7]);
  }
  float s = __shfl(ft[0], lane & 62, 64);   // k=0 (pre-poly) from even lane of pair
  const float* Wp = W_prod + layer * 96;
  float p0 = Wp[d], p1 = Wp[32 + d], p2 = Wp[64 + d];
  float poly = fmaf(fmaf(p2, s, p1), s, p0);
#pragma unroll
  for (int j = 0; j < 8; ++j) ft[j] *= poly;
  if (layer == 0 && kh == 0) ft[0] += sc_skip[n * CC + d];
  if (kh == 0) {
    scal_out[n * CC + d] = ft[0];
    lf[w][d][0] = ft[0]; lf[w][d][1] = ft[1]; lf[w][d][2] = ft[2]; lf[w][d][3] = ft[3];
  }
  __syncthreads();
  if (lane < 13) {
    float sum = 0.0f;
    if (lane < 10) {
      const float* Wr = W_ro_s + layer * CC * NEL;
      for (int dd = 0; dd < CC; ++dd) sum = fmaf(lf[w][dd][0], Wr[dd * NEL + lane], sum);
    } else {
      int mm = lane - 10;
      const float* Wv = W_ro_v + layer * CC;
      for (int dd = 0; dd < CC; ++dd) sum = fmaf(lf[w][dd][1 + mm], Wv[dd], sum);
    }
    pred[n * 13 + lane] += sum;
  }
}

// ---------------- K7: loss accumulation (hierarchical: LDS -> global) --------
__global__ __launch_bounds__(256) void k_loss(const float* __restrict__ pred,
    const float* __restrict__ eps, const int* __restrict__ batch,
    float* __restrict__ lnum, float* __restrict__ lcnt)
{
  __shared__ float psum[GG];
  __shared__ int pcnt[GG];
  int tid = threadIdx.x;
  if (tid < GG) { psum[tid] = 0.0f; pcnt[tid] = 0; }
  __syncthreads();
  int n = blockIdx.x * 256 + tid;
  if (n < NN) {
    int g = batch[n];
    float sum = 0.0f;
#pragma unroll
    for (int j = 0; j < 13; ++j) {
      float dlt = pred[n * 13 + j] - eps[n * 13 + j];
      sum = fmaf(dlt, dlt, sum);
    }
    atomicAdd(&psum[g], sum);   // LDS atomic; batch sorted -> 1-2 distinct g per block
    atomicAdd(&pcnt[g], 1);
  }
  __syncthreads();
  if (tid < GG && pcnt[tid] > 0) {
    atomicAdd(&lnum[tid], psum[tid]);
    atomicAdd(&lcnt[tid], (float)pcnt[tid]);
  }
}

__global__ void k_final(const float* __restrict__ lnum, const float* __restrict__ lcnt,
    float* __restrict__ out)
{
  int g = threadIdx.x;
  if (g < GG) {
    float nn = fmaxf(lcnt[g], 1.0f);
    out[g] = 0.5f * lnum[g] / (nn * 13.0f);
  }
}

extern "C" void kernel_launch(void* const* d_in, const int* in_sizes, int n_in,
                              void* d_out, int out_size, void* d_ws, size_t ws_size,
                              hipStream_t stream) {
  const float* positions  = (const float*)d_in[0];
  const float* node_attrs = (const float*)d_in[1];
  const float* shifts     = (const float*)d_in[2];
  const float* eps        = (const float*)d_in[3];
  const float* alpha_bar  = (const float*)d_in[4];
  const float* W_embed    = (const float*)d_in[5];
  const float* W_r1       = (const float*)d_in[6];
  const float* W_r2       = (const float*)d_in[7];
  const float* W_mix      = (const float*)d_in[8];
  const float* W_sc       = (const float*)d_in[9];
  const float* W_prod     = (const float*)d_in[10];
  const float* W_ro_s     = (const float*)d_in[11];
  const float* W_ro_v     = (const float*)d_in[12];
  const int* edge_index   = (const int*)d_in[13];
  const int* batch        = (const int*)d_in[14];
  const int* tarr         = (const int*)d_in[15];
  float* out = (float*)d_out;

  char* ws = (char*)d_ws;
  size_t off = 0;
  auto alloc = [&](size_t bytes) -> void* {
    void* p = ws + off;
    off = (off + bytes + 255) & ~(size_t)255;
    return p;
  };
  // total ~46 MB
  float* pos_noisy = (float*)alloc(NN * 3 * 4);
  float* scalA     = (float*)alloc(NN * CC * 4);
  float* scalB     = (float*)alloc(NN * CC * 4);
  float* sc_skip   = (float*)alloc(NN * CC * 4);
  float* pred      = (float*)alloc(NN * 13 * 4);
  ushort_t* Ys     = (ushort_t*)alloc((size_t)EE * 16 * 2);  // sorted, bf16
  ushort_t* efs    = (ushort_t*)alloc((size_t)EE * 8 * 2);   // sorted, bf16
  int* snds        = (int*)alloc((size_t)EE * 4);            // sorted sender ids
  ushort_t* rwc    = (ushort_t*)alloc((size_t)CAP * 128 * 2);// chunk rw, bf16 (20.5 MB)
  int* deg         = (int*)alloc(NN * 4);
  int* offs        = (int*)alloc((NN + 1) * 4);
  int* cursor      = (int*)alloc(NN * 4);
  float* lnum      = (float*)alloc(GG * 4);
  float* lcnt      = (float*)alloc(GG * 4);
  (void)ws_size; (void)in_sizes; (void)n_in; (void)out_size;

  const int NB_N = (NN + 255) / 256;   // 79
  const int NB_E = EE / 256;           // 1250

  k_prep<<<NB_N, 256, 0, stream>>>(positions, node_attrs, eps, alpha_bar, W_embed,
                                   W_sc, batch, tarr, pos_noisy, scalA, sc_skip, pred, deg);
  k_edge_deg<<<NB_E, 256, 0, stream>>>(edge_index, deg);
  k_scan<<<1, 1024, 0, stream>>>(deg, offs, cursor, lnum, lcnt);
  k_edge2<<<NB_E, 256, 0, stream>>>(pos_noisy, shifts, edge_index, cursor, Ys, efs, snds);

  for (int layer = 0; layer < 2; ++layer) {
    const float* sin_p = (layer == 0) ? scalA : scalB;
    float* sout_p      = (layer == 0) ? scalB : scalA;
    for (int ch = 0; ch < NN / CHN; ++ch) {
      int n0 = ch * CHN, n1 = n0 + CHN;
      k_rw<<<CAP / 64, 256, 0, stream>>>(efs, W_r1, W_r2, rwc, offs, layer, n0, n1);
      k_layer<<<CHN / 4, 256, 0, stream>>>(Ys, rwc, snds, sin_p, sout_p, offs,
                                           W_mix, W_prod, W_ro_s, W_ro_v,
                                           sc_skip, pred, layer, n0);
    }
  }

  k_loss<<<NB_N, 256, 0, stream>>>(pred, eps, batch, lnum, lcnt);
  k_final<<<1, 64, 0, stream>>>(lnum, lcnt, out);
}

// Round 6
// 362.413 us; speedup vs baseline: 2.6484x; 1.7240x over previous
//
#include <hip/hip_runtime.h>

typedef unsigned short ushort_t;
typedef unsigned int uint_t;

#define NN 20000
#define EE 320000
#define CC 32
#define NEL 10
#define GG 64
#define TTT 1000
#define NBB 8
#define HIDD 64
#define EPB 256         // edges per block in k_rw_mfma (EE = 1250*256 exactly)

typedef __attribute__((ext_vector_type(8))) short bf16x8;
typedef __attribute__((ext_vector_type(4))) float f32x4;

__device__ __forceinline__ float bits2f(uint_t b) { union { uint_t u; float f; } v; v.u = b; return v.f; }
__device__ __forceinline__ ushort_t f2b(float f) {
  union { float f; uint_t u; } v; v.f = f;
  uint_t r = (v.u + 0x7fffu + ((v.u >> 16) & 1u)) >> 16;
  return (ushort_t)r;
}
__device__ __forceinline__ uint_t pk(float a, float b) {
  return (uint_t)f2b(a) | ((uint_t)f2b(b) << 16);
}
__device__ __forceinline__ float lo16(uint_t u) { return bits2f(u << 16); }
__device__ __forceinline__ float hi16(uint_t u) { return bits2f(u & 0xffff0000u); }

// ---------------- K1: node prep (also zeroes deg) ----------------
__global__ __launch_bounds__(256) void k_prep(
    const float* __restrict__ positions, const float* __restrict__ node_attrs,
    const float* __restrict__ eps, const float* __restrict__ alpha_bar,
    const float* __restrict__ W_embed, const float* __restrict__ W_sc,
    const int* __restrict__ batch, const int* __restrict__ tarr,
    float* __restrict__ pos_noisy, float* __restrict__ scalA,
    float* __restrict__ sc_skip, float* __restrict__ pred, int* __restrict__ deg)
{
  int n = blockIdx.x * 256 + threadIdx.x;
  if (n >= NN) return;
  deg[n] = 0;
  int g = batch[n];
  int tn = tarr[g];
  float ab = alpha_bar[tn];
  float sa = sqrtf(ab), sb = sqrtf(fmaxf(1.0f - ab, 0.0f));
#pragma unroll
  for (int j = 0; j < 3; ++j)
    pos_noisy[n * 3 + j] = sa * positions[n * 3 + j] + sb * eps[n * 13 + 10 + j];
  float an[10];
#pragma unroll
  for (int j = 0; j < 10; ++j)
    an[j] = sa * 0.25f * node_attrs[n * 10 + j] + sb * eps[n * 13 + j];
  float tf = (float)tn * (1.0f / (float)TTT);
  for (int d = 0; d < CC; ++d) {
    float h = tf * W_embed[10 * CC + d];
    float sk = 0.0f;
#pragma unroll
    for (int j = 0; j < 10; ++j) {
      h = fmaf(an[j], W_embed[j * CC + d], h);
      sk = fmaf(an[j], W_sc[j * CC + d], sk);
    }
    scalA[n * CC + d] = h;
    sc_skip[n * CC + d] = sk;
  }
#pragma unroll
  for (int j = 0; j < 13; ++j) pred[n * 13 + j] = 0.0f;
}

// ---------------- K2a: receiver histogram ----------------
__global__ __launch_bounds__(256) void k_edge_deg(const int* __restrict__ ei,
    int* __restrict__ deg)
{
  int e = blockIdx.x * 256 + threadIdx.x;  // EE = 1250*256 exactly
  atomicAdd(&deg[ei[EE + e]], 1);
}

// ---------------- K3: exclusive scan deg -> offs, cursor; zero loss accum ----
__global__ __launch_bounds__(1024) void k_scan(const int* __restrict__ deg,
    int* __restrict__ offs, int* __restrict__ cursor,
    float* __restrict__ lnum, float* __restrict__ lcnt)
{
  __shared__ int wsums[16];
  __shared__ int woffs[16];
  int tid = threadIdx.x, lane = tid & 63, wv = tid >> 6;
  if (tid < GG) { lnum[tid] = 0.0f; lcnt[tid] = 0.0f; }
  int base = tid * 20;
  int loc[20];
  int s = 0;
#pragma unroll
  for (int j = 0; j < 20; ++j) {
    int idx = base + j;
    int v = (idx < NN) ? deg[idx] : 0;
    loc[j] = s; s += v;
  }
  int inc = s;
  for (int o = 1; o < 64; o <<= 1) {
    int v = __shfl_up(inc, o, 64);
    if (lane >= o) inc += v;
  }
  if (lane == 63) wsums[wv] = inc;
  __syncthreads();
  if (wv == 0 && lane < 16) {
    int v = wsums[lane];
    int i2 = v;
    for (int o = 1; o < 16; o <<= 1) {
      int vv = __shfl_up(i2, o, 16);
      if (lane >= o) i2 += vv;
    }
    woffs[lane] = i2 - v;
  }
  __syncthreads();
  int texcl = woffs[wv] + (inc - s);
#pragma unroll
  for (int j = 0; j < 20; ++j) {
    int idx = base + j;
    if (idx < NN) { int v = texcl + loc[j]; offs[idx] = v; cursor[idx] = v; }
  }
  if (tid == 1023) offs[NN] = EE;
}

// ---------------- K4: edge geometry, written into receiver-sorted slots ------
__global__ __launch_bounds__(256) void k_edge2(
    const float* __restrict__ pos_noisy, const float* __restrict__ shifts,
    const int* __restrict__ ei, int* __restrict__ cursor,
    ushort_t* __restrict__ Ys, ushort_t* __restrict__ efs, int* __restrict__ snds)
{
  int e = blockIdx.x * 256 + threadIdx.x;  // EE exact
  int snd = ei[e], rcv = ei[EE + e];
  float vx = pos_noisy[rcv * 3 + 0] - pos_noisy[snd * 3 + 0] + shifts[e * 3 + 0];
  float vy = pos_noisy[rcv * 3 + 1] - pos_noisy[snd * 3 + 1] + shifts[e * 3 + 1];
  float vz = pos_noisy[rcv * 3 + 2] - pos_noisy[snd * 3 + 2] + shifts[e * 3 + 2];
  float r2 = vx * vx + vy * vy + vz * vz + 1e-12f;
  float r = sqrtf(r2);
  float inv = 1.0f / r;
  float x = vx * inv, y = vy * inv, z = vz * inv;

  const float s3 = 1.7320508075688772f, s15 = 3.872983346207417f, s5 = 2.23606797749979f;
  const float s105 = 10.246950765959598f, s7 = 2.6457513110645907f;
  const float s35_8 = 2.091650066335189f, s21_8 = 1.6201851746019651f;
  float yv[16];
  yv[0] = 1.0f;
  yv[1] = s3 * x; yv[2] = s3 * y; yv[3] = s3 * z;
  yv[4] = s15 * x * y;
  yv[5] = s15 * y * z;
  yv[6] = 0.5f * s5 * (3.0f * z * z - 1.0f);
  yv[7] = s15 * x * z;
  yv[8] = 0.5f * s15 * (x * x - y * y);
  yv[9] = s35_8 * y * (3.0f * x * x - y * y);
  yv[10] = s105 * x * y * z;
  yv[11] = s21_8 * y * (5.0f * z * z - 1.0f);
  yv[12] = 0.5f * s7 * (5.0f * z * z * z - 3.0f * z);
  yv[13] = s21_8 * x * (5.0f * z * z - 1.0f);
  yv[14] = 0.5f * s105 * z * (x * x - y * y);
  yv[15] = s35_8 * x * (x * x - 3.0f * y * y);

  // radial embed: sqrt(2/5) * sin(n*pi*rc/5)/rc * poly_cutoff(r/5)
  float rc = fmaxf(r, 1e-9f);
  float pref = 0.6324555320336759f / rc;
  float th = 0.6283185307179586f * rc;
  float s1 = __sinf(th), c1 = __cosf(th);
  float xr = r * 0.2f;
  float fcut = 0.0f;
  if (xr < 1.0f) {
    float x2 = xr * xr, x3 = x2 * xr;
    float x6 = x3 * x3, x7 = x6 * xr, x8 = x7 * xr;
    fcut = 1.0f - 28.0f * x6 + 48.0f * x7 - 21.0f * x8;
  }
  float efv[8];
  float sp = 0.0f, scur = s1, c2 = 2.0f * c1;
#pragma unroll
  for (int b = 0; b < 8; ++b) {
    efv[b] = pref * scur * fcut;
    float nx = c2 * scur - sp;   // sin((n+1)th) = 2cos(th)sin(n th) - sin((n-1)th)
    sp = scur; scur = nx;
  }

  int slot = atomicAdd(&cursor[rcv], 1);
  snds[slot] = snd;
  uint4* Y4 = (uint4*)Ys;
  Y4[(size_t)slot * 2 + 0] = make_uint4(pk(yv[0], yv[1]), pk(yv[2], yv[3]),
                                        pk(yv[4], yv[5]), pk(yv[6], yv[7]));
  Y4[(size_t)slot * 2 + 1] = make_uint4(pk(yv[8], yv[9]), pk(yv[10], yv[11]),
                                        pk(yv[12], yv[13]), pk(yv[14], yv[15]));
  ((uint4*)efs)[slot] = make_uint4(pk(efv[0], efv[1]), pk(efv[2], efv[3]),
                                   pk(efv[4], efv[5]), pk(efv[6], efv[7]));
}

// ---------------- K5: edge radial MLP via MFMA (whole edge set) ---------------
// GEMM2: [E x 64] @ [64 x 128] in 16x16x32 bf16 MFMA.
// Verified layouts (m89/m91/m120): A[m=lane&15][k=quad*8+j], B[k=quad*8+j][n=lane&15],
// D: col=lane&15, row=quad*4+reg.
__global__ __launch_bounds__(256) void k_rw_mfma(
    const ushort_t* __restrict__ efs, const float* __restrict__ W_r1,
    const float* __restrict__ W_r2, ushort_t* __restrict__ rwc, int layer)
{
  __shared__ __align__(16) ushort_t w2t[128][72];   // W2^T bf16, padded (+8)
  __shared__ __align__(16) ushort_t h1[EPB][72];    // silu(ef@W1) bf16, padded
  int tid = threadIdx.x;
  const float* W1g = W_r1 + layer * NBB * HIDD;
  const float* W2g = W_r2 + layer * HIDD * 128;
  // stage W2 transposed -> bf16 LDS
  for (int idx = tid; idx < HIDD * 128; idx += 256) {
    int k = idx >> 7, n = idx & 127;
    w2t[n][k] = f2b(W2g[idx]);
  }
  // h1 for this thread's edge (one edge per thread)
  {
    int e = blockIdx.x * EPB + tid;
    uint4 q = ((const uint4*)efs)[e];
    float efr[8] = {lo16(q.x), hi16(q.x), lo16(q.y), hi16(q.y),
                    lo16(q.z), hi16(q.z), lo16(q.w), hi16(q.w)};
    for (int hc = 0; hc < 8; ++hc) {
      float v[8];
#pragma unroll
      for (int hh = 0; hh < 8; ++hh) {
        int h = hc * 8 + hh;
        float t = 0.0f;
#pragma unroll
        for (int b = 0; b < 8; ++b) t = fmaf(efr[b], W1g[b * HIDD + h], t);
        v[hh] = t / (1.0f + __expf(-t));   // silu
      }
      *(uint4*)&h1[tid][hc * 8] = make_uint4(pk(v[0], v[1]), pk(v[2], v[3]),
                                             pk(v[4], v[5]), pk(v[6], v[7]));
    }
  }
  __syncthreads();
  int w = tid >> 6, lane = tid & 63;
  int c = lane & 15, quad = lane >> 4;
  // all 16 B-fragments (8 n-tiles x 2 k-tiles) in registers
  bf16x8 bfr[16];
#pragma unroll
  for (int nt = 0; nt < 8; ++nt)
#pragma unroll
    for (int kt = 0; kt < 2; ++kt)
      bfr[nt * 2 + kt] = *(const bf16x8*)&w2t[nt * 16 + c][kt * 32 + quad * 8];
  int mb0 = w * 64;   // this wave covers 64 edges = 4 m-tiles
#pragma unroll
  for (int mt = 0; mt < 4; ++mt) {
    int mbase = mb0 + mt * 16;
    bf16x8 a0 = *(const bf16x8*)&h1[mbase + c][quad * 8];
    bf16x8 a1 = *(const bf16x8*)&h1[mbase + c][32 + quad * 8];
    size_t erow = (size_t)blockIdx.x * EPB + mbase + quad * 4;
#pragma unroll
    for (int nt = 0; nt < 8; ++nt) {
      f32x4 acc = {0.0f, 0.0f, 0.0f, 0.0f};
      acc = __builtin_amdgcn_mfma_f32_16x16x32_bf16(a0, bfr[nt * 2 + 0], acc, 0, 0, 0);
      acc = __builtin_amdgcn_mfma_f32_16x16x32_bf16(a1, bfr[nt * 2 + 1], acc, 0, 0, 0);
      int col = nt * 16 + c;
#pragma unroll
      for (int r = 0; r < 4; ++r)
        rwc[(erow + r) * 128 + col] = f2b(acc[r]);
    }
  }
}

// ---------------- K6: fused aggregate + mix + poly + readout ------------------
__global__ __launch_bounds__(256) void k_layer(
    const ushort_t* __restrict__ Ys, const ushort_t* __restrict__ rwc,
    const int* __restrict__ snds,
    const float* __restrict__ scal_in, float* __restrict__ scal_out,
    const int* __restrict__ offs,
    const float* __restrict__ W_mix, const float* __restrict__ W_prod,
    const float* __restrict__ W_ro_s, const float* __restrict__ W_ro_v,
    const float* __restrict__ sc_skip, float* __restrict__ pred, int layer)
{
  __shared__ float lagg[4][CC][16];
  __shared__ float lf[4][CC][4];
  int w = threadIdx.x >> 6, lane = threadIdx.x & 63;
  int n = blockIdx.x * 4 + w;        // NN = 5000*4 exactly
  int c = lane >> 1;
  int kh = lane & 1;
  int kb = kh * 8;
  int i0 = offs[n], i1 = offs[n + 1];
  float acc0 = 0, acc1 = 0, acc2 = 0, acc3 = 0, acc4 = 0, acc5 = 0, acc6 = 0, acc7 = 0;
  const uint4* Y4 = (const uint4*)Ys;
  const uint2* rw2 = (const uint2*)rwc;
  for (int s = i0; s < i1; ++s) {
    uint4 q = Y4[(size_t)s * 2 + kh];
    uint2 rp = rw2[(size_t)s * 32 + c];
    float ss = scal_in[snds[s] * CC + c];
    float r0 = lo16(rp.x), r1 = hi16(rp.x), r2v = lo16(rp.y), r3 = hi16(rp.y);
    // L_OF_LM: kh0 -> l={0,1,1,1,2,2,2,2}; kh1 -> l={2,3,3,3,3,3,3,3}
    float w0 = kh ? r2v : r0;
    float w13 = kh ? r3 : r1;
    float w47 = kh ? r3 : r2v;
    float ya0 = lo16(q.x), ya1 = hi16(q.x), ya2 = lo16(q.y), ya3 = hi16(q.y);
    float yb0 = lo16(q.z), yb1 = hi16(q.z), yb2 = lo16(q.w), yb3 = hi16(q.w);
    acc0 = fmaf(w0 * ss, ya0, acc0);
    acc1 = fmaf(w13 * ss, ya1, acc1);
    acc2 = fmaf(w13 * ss, ya2, acc2);
    acc3 = fmaf(w13 * ss, ya3, acc3);
    acc4 = fmaf(w47 * ss, yb0, acc4);
    acc5 = fmaf(w47 * ss, yb1, acc5);
    acc6 = fmaf(w47 * ss, yb2, acc6);
    acc7 = fmaf(w47 * ss, yb3, acc7);
  }
  const float invavg = 1.0f / 16.0f;
  lagg[w][c][kb + 0] = acc0 * invavg;
  lagg[w][c][kb + 1] = acc1 * invavg;
  lagg[w][c][kb + 2] = acc2 * invavg;
  lagg[w][c][kb + 3] = acc3 * invavg;
  lagg[w][c][kb + 4] = acc4 * invavg;
  lagg[w][c][kb + 5] = acc5 * invavg;
  lagg[w][c][kb + 6] = acc6 * invavg;
  lagg[w][c][kb + 7] = acc7 * invavg;
  __syncthreads();
  int d = c;
  float ft[8] = {0, 0, 0, 0, 0, 0, 0, 0};
  const float* Wm = W_mix + layer * 4096;
  for (int cc2 = 0; cc2 < CC; ++cc2) {
    float m0 = Wm[cc2 * CC + d];
    float m1 = Wm[1024 + cc2 * CC + d];
    float m2 = Wm[2048 + cc2 * CC + d];
    float m3 = Wm[3072 + cc2 * CC + d];
    float u0 = kh ? m2 : m0;
    float u13 = kh ? m3 : m1;
    float u47 = kh ? m3 : m2;
    ft[0] = fmaf(lagg[w][cc2][kb + 0], u0, ft[0]);
    ft[1] = fmaf(lagg[w][cc2][kb + 1], u13, ft[1]);
    ft[2] = fmaf(lagg[w][cc2][kb + 2], u13, ft[2]);
    ft[3] = fmaf(lagg[w][cc2][kb + 3], u13, ft[3]);
    ft[4] = fmaf(lagg[w][cc2][kb + 4], u47, ft[4]);
    ft[5] = fmaf(lagg[w][cc2][kb + 5], u47, ft[5]);
    ft[6] = fmaf(lagg[w][cc2][kb + 6], u47, ft[6]);
    ft[7] = fmaf(lagg[w][cc2][kb + 7], u47, ft[7]);
  }
  float s = __shfl(ft[0], lane & 62, 64);   // k=0 (pre-poly) from even lane of pair
  const float* Wp = W_prod + layer * 96;
  float p0 = Wp[d], p1 = Wp[32 + d], p2 = Wp[64 + d];
  float poly = fmaf(fmaf(p2, s, p1), s, p0);
#pragma unroll
  for (int j = 0; j < 8; ++j) ft[j] *= poly;
  if (layer == 0 && kh == 0) ft[0] += sc_skip[n * CC + d];
  if (kh == 0) {
    scal_out[n * CC + d] = ft[0];
    lf[w][d][0] = ft[0]; lf[w][d][1] = ft[1]; lf[w][d][2] = ft[2]; lf[w][d][3] = ft[3];
  }
  __syncthreads();
  if (lane < 13) {
    float sum = 0.0f;
    if (lane < 10) {
      const float* Wr = W_ro_s + layer * CC * NEL;
      for (int dd = 0; dd < CC; ++dd) sum = fmaf(lf[w][dd][0], Wr[dd * NEL + lane], sum);
    } else {
      int mm = lane - 10;
      const float* Wv = W_ro_v + layer * CC;
      for (int dd = 0; dd < CC; ++dd) sum = fmaf(lf[w][dd][1 + mm], Wv[dd], sum);
    }
    pred[n * 13 + lane] += sum;
  }
}

// ---------------- K7: loss accumulation (hierarchical: LDS -> global) --------
__global__ __launch_bounds__(256) void k_loss(const float* __restrict__ pred,
    const float* __restrict__ eps, const int* __restrict__ batch,
    float* __restrict__ lnum, float* __restrict__ lcnt)
{
  __shared__ float psum[GG];
  __shared__ int pcnt[GG];
  int tid = threadIdx.x;
  if (tid < GG) { psum[tid] = 0.0f; pcnt[tid] = 0; }
  __syncthreads();
  int n = blockIdx.x * 256 + tid;
  if (n < NN) {
    int g = batch[n];
    float sum = 0.0f;
#pragma unroll
    for (int j = 0; j < 13; ++j) {
      float dlt = pred[n * 13 + j] - eps[n * 13 + j];
      sum = fmaf(dlt, dlt, sum);
    }
    atomicAdd(&psum[g], sum);   // LDS atomic; batch sorted -> 1-2 distinct g per block
    atomicAdd(&pcnt[g], 1);
  }
  __syncthreads();
  if (tid < GG && pcnt[tid] > 0) {
    atomicAdd(&lnum[tid], psum[tid]);
    atomicAdd(&lcnt[tid], (float)pcnt[tid]);
  }
}

__global__ void k_final(const float* __restrict__ lnum, const float* __restrict__ lcnt,
    float* __restrict__ out)
{
  int g = threadIdx.x;
  if (g < GG) {
    float nn = fmaxf(lcnt[g], 1.0f);
    out[g] = 0.5f * lnum[g] / (nn * 13.0f);
  }
}

extern "C" void kernel_launch(void* const* d_in, const int* in_sizes, int n_in,
                              void* d_out, int out_size, void* d_ws, size_t ws_size,
                              hipStream_t stream) {
  const float* positions  = (const float*)d_in[0];
  const float* node_attrs = (const float*)d_in[1];
  const float* shifts     = (const float*)d_in[2];
  const float* eps        = (const float*)d_in[3];
  const float* alpha_bar  = (const float*)d_in[4];
  const float* W_embed    = (const float*)d_in[5];
  const float* W_r1       = (const float*)d_in[6];
  const float* W_r2       = (const float*)d_in[7];
  const float* W_mix      = (const float*)d_in[8];
  const float* W_sc       = (const float*)d_in[9];
  const float* W_prod     = (const float*)d_in[10];
  const float* W_ro_s     = (const float*)d_in[11];
  const float* W_ro_v     = (const float*)d_in[12];
  const int* edge_index   = (const int*)d_in[13];
  const int* batch        = (const int*)d_in[14];
  const int* tarr         = (const int*)d_in[15];
  float* out = (float*)d_out;

  char* ws = (char*)d_ws;
  size_t off = 0;
  auto alloc = [&](size_t bytes) -> void* {
    void* p = ws + off;
    off = (off + bytes + 255) & ~(size_t)255;
    return p;
  };
  // total ~107 MB (ws_size = 256 MiB per round-5 fillBuffer evidence)
  float* pos_noisy = (float*)alloc(NN * 3 * 4);
  float* scalA     = (float*)alloc(NN * CC * 4);
  float* scalB     = (float*)alloc(NN * CC * 4);
  float* sc_skip   = (float*)alloc(NN * CC * 4);
  float* pred      = (float*)alloc(NN * 13 * 4);
  ushort_t* Ys     = (ushort_t*)alloc((size_t)EE * 16 * 2);  // sorted, bf16
  ushort_t* efs    = (ushort_t*)alloc((size_t)EE * 8 * 2);   // sorted, bf16
  int* snds        = (int*)alloc((size_t)EE * 4);            // sorted sender ids
  ushort_t* rwc    = (ushort_t*)alloc((size_t)EE * 128 * 2); // full rw, bf16 (82 MB)
  int* deg         = (int*)alloc(NN * 4);
  int* offs        = (int*)alloc((NN + 1) * 4);
  int* cursor      = (int*)alloc(NN * 4);
  float* lnum      = (float*)alloc(GG * 4);
  float* lcnt      = (float*)alloc(GG * 4);
  (void)ws_size; (void)in_sizes; (void)n_in; (void)out_size;

  const int NB_N = (NN + 255) / 256;   // 79
  const int NB_E = EE / 256;           // 1250

  k_prep<<<NB_N, 256, 0, stream>>>(positions, node_attrs, eps, alpha_bar, W_embed,
                                   W_sc, batch, tarr, pos_noisy, scalA, sc_skip, pred, deg);
  k_edge_deg<<<NB_E, 256, 0, stream>>>(edge_index, deg);
  k_scan<<<1, 1024, 0, stream>>>(deg, offs, cursor, lnum, lcnt);
  k_edge2<<<NB_E, 256, 0, stream>>>(pos_noisy, shifts, edge_index, cursor, Ys, efs, snds);

  for (int layer = 0; layer < 2; ++layer) {
    const float* sin_p = (layer == 0) ? scalA : scalB;
    float* sout_p      = (layer == 0) ? scalB : scalA;
    k_rw_mfma<<<NB_E, 256, 0, stream>>>(efs, W_r1, W_r2, rwc, layer);
    k_layer<<<NN / 4, 256, 0, stream>>>(Ys, rwc, snds, sin_p, sout_p, offs,
                                        W_mix, W_prod, W_ro_s, W_ro_v,
                                        sc_skip, pred, layer);
  }

  k_loss<<<NB_N, 256, 0, stream>>>(pred, eps, batch, lnum, lcnt);
  k_final<<<1, 64, 0, stream>>>(lnum, lcnt, out);
}

// Round 7
// 341.642 us; speedup vs baseline: 2.8094x; 1.0608x over previous
//
#include <hip/hip_runtime.h>

typedef unsigned short ushort_t;
typedef unsigned int uint_t;

#define NN 20000
#define EE 320000
#define CC 32
#define NEL 10
#define GG 64
#define TTT 1000
#define NBB 8
#define HIDD 64
#define EPB 256         // edges per block in k_rw_mfma (EE = 1250*256 exactly)

typedef __attribute__((ext_vector_type(8))) short bf16x8;
typedef __attribute__((ext_vector_type(4))) float f32x4;

__device__ __forceinline__ float bits2f(uint_t b) { union { uint_t u; float f; } v; v.u = b; return v.f; }
__device__ __forceinline__ ushort_t f2b(float f) {
  union { float f; uint_t u; } v; v.f = f;
  uint_t r = (v.u + 0x7fffu + ((v.u >> 16) & 1u)) >> 16;
  return (ushort_t)r;
}
__device__ __forceinline__ uint_t pk(float a, float b) {
  return (uint_t)f2b(a) | ((uint_t)f2b(b) << 16);
}
__device__ __forceinline__ float lo16(uint_t u) { return bits2f(u << 16); }
__device__ __forceinline__ float hi16(uint_t u) { return bits2f(u & 0xffff0000u); }

// ---------------- K1: node prep (also zeroes deg) ----------------
__global__ __launch_bounds__(256) void k_prep(
    const float* __restrict__ positions, const float* __restrict__ node_attrs,
    const float* __restrict__ eps, const float* __restrict__ alpha_bar,
    const float* __restrict__ W_embed, const float* __restrict__ W_sc,
    const int* __restrict__ batch, const int* __restrict__ tarr,
    float* __restrict__ pos_noisy, float* __restrict__ scalA,
    float* __restrict__ sc_skip, float* __restrict__ pred, int* __restrict__ deg)
{
  int n = blockIdx.x * 256 + threadIdx.x;
  if (n >= NN) return;
  deg[n] = 0;
  int g = batch[n];
  int tn = tarr[g];
  float ab = alpha_bar[tn];
  float sa = sqrtf(ab), sb = sqrtf(fmaxf(1.0f - ab, 0.0f));
#pragma unroll
  for (int j = 0; j < 3; ++j)
    pos_noisy[n * 3 + j] = sa * positions[n * 3 + j] + sb * eps[n * 13 + 10 + j];
  float an[10];
#pragma unroll
  for (int j = 0; j < 10; ++j)
    an[j] = sa * 0.25f * node_attrs[n * 10 + j] + sb * eps[n * 13 + j];
  float tf = (float)tn * (1.0f / (float)TTT);
  for (int d = 0; d < CC; ++d) {
    float h = tf * W_embed[10 * CC + d];
    float sk = 0.0f;
#pragma unroll
    for (int j = 0; j < 10; ++j) {
      h = fmaf(an[j], W_embed[j * CC + d], h);
      sk = fmaf(an[j], W_sc[j * CC + d], sk);
    }
    scalA[n * CC + d] = h;
    sc_skip[n * CC + d] = sk;
  }
#pragma unroll
  for (int j = 0; j < 13; ++j) pred[n * 13 + j] = 0.0f;
}

// ---------------- K2a: receiver histogram ----------------
__global__ __launch_bounds__(256) void k_edge_deg(const int* __restrict__ ei,
    int* __restrict__ deg)
{
  int e = blockIdx.x * 256 + threadIdx.x;  // EE = 1250*256 exactly
  atomicAdd(&deg[ei[EE + e]], 1);
}

// ---------------- K3: exclusive scan deg -> offs, cursor; zero loss accum ----
__global__ __launch_bounds__(1024) void k_scan(const int* __restrict__ deg,
    int* __restrict__ offs, int* __restrict__ cursor,
    float* __restrict__ lnum, float* __restrict__ lcnt)
{
  __shared__ int wsums[16];
  __shared__ int woffs[16];
  int tid = threadIdx.x, lane = tid & 63, wv = tid >> 6;
  if (tid < GG) { lnum[tid] = 0.0f; lcnt[tid] = 0.0f; }
  int base = tid * 20;
  int loc[20];
  int s = 0;
#pragma unroll
  for (int j = 0; j < 20; ++j) {
    int idx = base + j;
    int v = (idx < NN) ? deg[idx] : 0;
    loc[j] = s; s += v;
  }
  int inc = s;
  for (int o = 1; o < 64; o <<= 1) {
    int v = __shfl_up(inc, o, 64);
    if (lane >= o) inc += v;
  }
  if (lane == 63) wsums[wv] = inc;
  __syncthreads();
  if (wv == 0 && lane < 16) {
    int v = wsums[lane];
    int i2 = v;
    for (int o = 1; o < 16; o <<= 1) {
      int vv = __shfl_up(i2, o, 16);
      if (lane >= o) i2 += vv;
    }
    woffs[lane] = i2 - v;
  }
  __syncthreads();
  int texcl = woffs[wv] + (inc - s);
#pragma unroll
  for (int j = 0; j < 20; ++j) {
    int idx = base + j;
    if (idx < NN) { int v = texcl + loc[j]; offs[idx] = v; cursor[idx] = v; }
  }
  if (tid == 1023) offs[NN] = EE;
}

// ---------------- K4: edge geometry, written into receiver-sorted slots ------
__global__ __launch_bounds__(256) void k_edge2(
    const float* __restrict__ pos_noisy, const float* __restrict__ shifts,
    const int* __restrict__ ei, int* __restrict__ cursor,
    ushort_t* __restrict__ Ys, ushort_t* __restrict__ efs, int* __restrict__ snds)
{
  int e = blockIdx.x * 256 + threadIdx.x;  // EE exact
  int snd = ei[e], rcv = ei[EE + e];
  float vx = pos_noisy[rcv * 3 + 0] - pos_noisy[snd * 3 + 0] + shifts[e * 3 + 0];
  float vy = pos_noisy[rcv * 3 + 1] - pos_noisy[snd * 3 + 1] + shifts[e * 3 + 1];
  float vz = pos_noisy[rcv * 3 + 2] - pos_noisy[snd * 3 + 2] + shifts[e * 3 + 2];
  float r2 = vx * vx + vy * vy + vz * vz + 1e-12f;
  float r = sqrtf(r2);
  float inv = 1.0f / r;
  float x = vx * inv, y = vy * inv, z = vz * inv;

  const float s3 = 1.7320508075688772f, s15 = 3.872983346207417f, s5 = 2.23606797749979f;
  const float s105 = 10.246950765959598f, s7 = 2.6457513110645907f;
  const float s35_8 = 2.091650066335189f, s21_8 = 1.6201851746019651f;
  float yv[16];
  yv[0] = 1.0f;
  yv[1] = s3 * x; yv[2] = s3 * y; yv[3] = s3 * z;
  yv[4] = s15 * x * y;
  yv[5] = s15 * y * z;
  yv[6] = 0.5f * s5 * (3.0f * z * z - 1.0f);
  yv[7] = s15 * x * z;
  yv[8] = 0.5f * s15 * (x * x - y * y);
  yv[9] = s35_8 * y * (3.0f * x * x - y * y);
  yv[10] = s105 * x * y * z;
  yv[11] = s21_8 * y * (5.0f * z * z - 1.0f);
  yv[12] = 0.5f * s7 * (5.0f * z * z * z - 3.0f * z);
  yv[13] = s21_8 * x * (5.0f * z * z - 1.0f);
  yv[14] = 0.5f * s105 * z * (x * x - y * y);
  yv[15] = s35_8 * x * (x * x - 3.0f * y * y);

  // radial embed: sqrt(2/5) * sin(n*pi*rc/5)/rc * poly_cutoff(r/5)
  float rc = fmaxf(r, 1e-9f);
  float pref = 0.6324555320336759f / rc;
  float th = 0.6283185307179586f * rc;
  float s1 = __sinf(th), c1 = __cosf(th);
  float xr = r * 0.2f;
  float fcut = 0.0f;
  if (xr < 1.0f) {
    float x2 = xr * xr, x3 = x2 * xr;
    float x6 = x3 * x3, x7 = x6 * xr, x8 = x7 * xr;
    fcut = 1.0f - 28.0f * x6 + 48.0f * x7 - 21.0f * x8;
  }
  float efv[8];
  float sp = 0.0f, scur = s1, c2 = 2.0f * c1;
#pragma unroll
  for (int b = 0; b < 8; ++b) {
    efv[b] = pref * scur * fcut;
    float nx = c2 * scur - sp;   // sin((n+1)th) = 2cos(th)sin(n th) - sin((n-1)th)
    sp = scur; scur = nx;
  }

  int slot = atomicAdd(&cursor[rcv], 1);
  snds[slot] = snd;
  uint4* Y4 = (uint4*)Ys;
  Y4[(size_t)slot * 2 + 0] = make_uint4(pk(yv[0], yv[1]), pk(yv[2], yv[3]),
                                        pk(yv[4], yv[5]), pk(yv[6], yv[7]));
  Y4[(size_t)slot * 2 + 1] = make_uint4(pk(yv[8], yv[9]), pk(yv[10], yv[11]),
                                        pk(yv[12], yv[13]), pk(yv[14], yv[15]));
  ((uint4*)efs)[slot] = make_uint4(pk(efv[0], efv[1]), pk(efv[2], efv[3]),
                                   pk(efv[4], efv[5]), pk(efv[6], efv[7]));
}

// ---------------- K5: edge radial MLP via MFMA, ss folded into epilogue ------
// GEMM2: [E x 64] @ [64 x 128] in 16x16x32 bf16 MFMA; rwc[e,col] *= scal_in[snd[e], col>>2]
__global__ __launch_bounds__(256) void k_rw_mfma(
    const ushort_t* __restrict__ efs, const float* __restrict__ W_r1,
    const float* __restrict__ W_r2, const int* __restrict__ snds,
    const float* __restrict__ scal_in, ushort_t* __restrict__ rwc, int layer)
{
  __shared__ __align__(16) ushort_t w2t[128][72];   // W2^T bf16, padded (+8)
  __shared__ __align__(16) ushort_t h1[EPB][72];    // silu(ef@W1) bf16, padded
  int tid = threadIdx.x;
  const float* W1g = W_r1 + layer * NBB * HIDD;
  const float* W2g = W_r2 + layer * HIDD * 128;
  // stage W2 transposed -> bf16 LDS
  for (int idx = tid; idx < HIDD * 128; idx += 256) {
    int k = idx >> 7, n = idx & 127;
    w2t[n][k] = f2b(W2g[idx]);
  }
  // h1 for this thread's edge (one edge per thread)
  {
    int e = blockIdx.x * EPB + tid;
    uint4 q = ((const uint4*)efs)[e];
    float efr[8] = {lo16(q.x), hi16(q.x), lo16(q.y), hi16(q.y),
                    lo16(q.z), hi16(q.z), lo16(q.w), hi16(q.w)};
    for (int hc = 0; hc < 8; ++hc) {
      float v[8];
#pragma unroll
      for (int hh = 0; hh < 8; ++hh) {
        int h = hc * 8 + hh;
        float t = 0.0f;
#pragma unroll
        for (int b = 0; b < 8; ++b) t = fmaf(efr[b], W1g[b * HIDD + h], t);
        v[hh] = t / (1.0f + __expf(-t));   // silu
      }
      *(uint4*)&h1[tid][hc * 8] = make_uint4(pk(v[0], v[1]), pk(v[2], v[3]),
                                             pk(v[4], v[5]), pk(v[6], v[7]));
    }
  }
  __syncthreads();
  int w = tid >> 6, lane = tid & 63;
  int c = lane & 15, quad = lane >> 4;
  // all 16 B-fragments (8 n-tiles x 2 k-tiles) in registers
  bf16x8 bfr[16];
#pragma unroll
  for (int nt = 0; nt < 8; ++nt)
#pragma unroll
    for (int kt = 0; kt < 2; ++kt)
      bfr[nt * 2 + kt] = *(const bf16x8*)&w2t[nt * 16 + c][kt * 32 + quad * 8];
  int mb0 = w * 64;   // this wave covers 64 edges = 4 m-tiles
#pragma unroll
  for (int mt = 0; mt < 4; ++mt) {
    int mbase = mb0 + mt * 16;
    bf16x8 a0 = *(const bf16x8*)&h1[mbase + c][quad * 8];
    bf16x8 a1 = *(const bf16x8*)&h1[mbase + c][32 + quad * 8];
    size_t erow = (size_t)blockIdx.x * EPB + mbase + quad * 4;
    int4 sn = *(const int4*)&snds[erow];     // 4 consecutive edges' senders
    const float* sb0 = scal_in + (size_t)sn.x * CC;
    const float* sb1 = scal_in + (size_t)sn.y * CC;
    const float* sb2 = scal_in + (size_t)sn.z * CC;
    const float* sb3 = scal_in + (size_t)sn.w * CC;
#pragma unroll
    for (int nt = 0; nt < 8; ++nt) {
      f32x4 acc = {0.0f, 0.0f, 0.0f, 0.0f};
      acc = __builtin_amdgcn_mfma_f32_16x16x32_bf16(a0, bfr[nt * 2 + 0], acc, 0, 0, 0);
      acc = __builtin_amdgcn_mfma_f32_16x16x32_bf16(a1, bfr[nt * 2 + 1], acc, 0, 0, 0);
      int col = nt * 16 + c;
      int cc = col >> 2;                     // channel = col/4 (col = 4c+l)
      rwc[(erow + 0) * 128 + col] = f2b(acc[0] * sb0[cc]);
      rwc[(erow + 1) * 128 + col] = f2b(acc[1] * sb1[cc]);
      rwc[(erow + 2) * 128 + col] = f2b(acc[2] * sb2[cc]);
      rwc[(erow + 3) * 128 + col] = f2b(acc[3] * sb3[cc]);
    }
  }
}

// ---------------- K6: streaming aggregate + mix + poly + readout --------------
__global__ __launch_bounds__(256) void k_layer(
    const ushort_t* __restrict__ Ys, const ushort_t* __restrict__ rwc,
    float* __restrict__ scal_out,
    const int* __restrict__ offs,
    const float* __restrict__ W_mix, const float* __restrict__ W_prod,
    const float* __restrict__ W_ro_s, const float* __restrict__ W_ro_v,
    const float* __restrict__ sc_skip, float* __restrict__ pred, int layer)
{
  __shared__ float lagg[4][CC][16];
  __shared__ float lf[4][CC][4];
  int w = threadIdx.x >> 6, lane = threadIdx.x & 63;
  int n = blockIdx.x * 4 + w;        // NN = 5000*4 exactly
  int c = lane >> 1;
  int kh = lane & 1;
  int kb = kh * 8;
  int i0 = offs[n], i1 = offs[n + 1];
  float acc0 = 0, acc1 = 0, acc2 = 0, acc3 = 0, acc4 = 0, acc5 = 0, acc6 = 0, acc7 = 0;
  const uint4* Y4 = (const uint4*)Ys;
  const uint2* rw2 = (const uint2*)rwc;
  int s = i0;
  // pure streaming: no gathers, no dependent chains; unroll x2 for MLP
  for (; s + 2 <= i1; s += 2) {
    uint4 qa = Y4[(size_t)s * 2 + kh];
    uint2 ra = rw2[(size_t)s * 32 + c];
    uint4 qb = Y4[(size_t)(s + 1) * 2 + kh];
    uint2 rb = rw2[(size_t)(s + 1) * 32 + c];
    {
      float r0 = lo16(ra.x), r1 = hi16(ra.x), r2v = lo16(ra.y), r3 = hi16(ra.y);
      float w0 = kh ? r2v : r0, w13 = kh ? r3 : r1, w47 = kh ? r3 : r2v;
      acc0 = fmaf(w0,  lo16(qa.x), acc0);
      acc1 = fmaf(w13, hi16(qa.x), acc1);
      acc2 = fmaf(w13, lo16(qa.y), acc2);
      acc3 = fmaf(w13, hi16(qa.y), acc3);
      acc4 = fmaf(w47, lo16(qa.z), acc4);
      acc5 = fmaf(w47, hi16(qa.z), acc5);
      acc6 = fmaf(w47, lo16(qa.w), acc6);
      acc7 = fmaf(w47, hi16(qa.w), acc7);
    }
    {
      float r0 = lo16(rb.x), r1 = hi16(rb.x), r2v = lo16(rb.y), r3 = hi16(rb.y);
      float w0 = kh ? r2v : r0, w13 = kh ? r3 : r1, w47 = kh ? r3 : r2v;
      acc0 = fmaf(w0,  lo16(qb.x), acc0);
      acc1 = fmaf(w13, hi16(qb.x), acc1);
      acc2 = fmaf(w13, lo16(qb.y), acc2);
      acc3 = fmaf(w13, hi16(qb.y), acc3);
      acc4 = fmaf(w47, lo16(qb.z), acc4);
      acc5 = fmaf(w47, hi16(qb.z), acc5);
      acc6 = fmaf(w47, lo16(qb.w), acc6);
      acc7 = fmaf(w47, hi16(qb.w), acc7);
    }
  }
  if (s < i1) {
    uint4 q = Y4[(size_t)s * 2 + kh];
    uint2 rp = rw2[(size_t)s * 32 + c];
    float r0 = lo16(rp.x), r1 = hi16(rp.x), r2v = lo16(rp.y), r3 = hi16(rp.y);
    float w0 = kh ? r2v : r0, w13 = kh ? r3 : r1, w47 = kh ? r3 : r2v;
    acc0 = fmaf(w0,  lo16(q.x), acc0);
    acc1 = fmaf(w13, hi16(q.x), acc1);
    acc2 = fmaf(w13, lo16(q.y), acc2);
    acc3 = fmaf(w13, hi16(q.y), acc3);
    acc4 = fmaf(w47, lo16(q.z), acc4);
    acc5 = fmaf(w47, hi16(q.z), acc5);
    acc6 = fmaf(w47, lo16(q.w), acc6);
    acc7 = fmaf(w47, hi16(q.w), acc7);
  }
  const float invavg = 1.0f / 16.0f;
  lagg[w][c][kb + 0] = acc0 * invavg;
  lagg[w][c][kb + 1] = acc1 * invavg;
  lagg[w][c][kb + 2] = acc2 * invavg;
  lagg[w][c][kb + 3] = acc3 * invavg;
  lagg[w][c][kb + 4] = acc4 * invavg;
  lagg[w][c][kb + 5] = acc5 * invavg;
  lagg[w][c][kb + 6] = acc6 * invavg;
  lagg[w][c][kb + 7] = acc7 * invavg;
  __syncthreads();
  int d = c;
  float ft[8] = {0, 0, 0, 0, 0, 0, 0, 0};
  const float* Wm = W_mix + layer * 4096;
  for (int cc2 = 0; cc2 < CC; ++cc2) {
    float m0 = Wm[cc2 * CC + d];
    float m1 = Wm[1024 + cc2 * CC + d];
    float m2 = Wm[2048 + cc2 * CC + d];
    float m3 = Wm[3072 + cc2 * CC + d];
    float u0 = kh ? m2 : m0;
    float u13 = kh ? m3 : m1;
    float u47 = kh ? m3 : m2;
    ft[0] = fmaf(lagg[w][cc2][kb + 0], u0, ft[0]);
    ft[1] = fmaf(lagg[w][cc2][kb + 1], u13, ft[1]);
    ft[2] = fmaf(lagg[w][cc2][kb + 2], u13, ft[2]);
    ft[3] = fmaf(lagg[w][cc2][kb + 3], u13, ft[3]);
    ft[4] = fmaf(lagg[w][cc2][kb + 4], u47, ft[4]);
    ft[5] = fmaf(lagg[w][cc2][kb + 5], u47, ft[5]);
    ft[6] = fmaf(lagg[w][cc2][kb + 6], u47, ft[6]);
    ft[7] = fmaf(lagg[w][cc2][kb + 7], u47, ft[7]);
  }
  float sv = __shfl(ft[0], lane & 62, 64);   // k=0 (pre-poly) from even lane of pair
  const float* Wp = W_prod + layer * 96;
  float p0 = Wp[d], p1 = Wp[32 + d], p2 = Wp[64 + d];
  float poly = fmaf(fmaf(p2, sv, p1), sv, p0);
#pragma unroll
  for (int j = 0; j < 8; ++j) ft[j] *= poly;
  if (layer == 0 && kh == 0) ft[0] += sc_skip[n * CC + d];
  if (kh == 0) {
    scal_out[n * CC + d] = ft[0];
    lf[w][d][0] = ft[0]; lf[w][d][1] = ft[1]; lf[w][d][2] = ft[2]; lf[w][d][3] = ft[3];
  }
  __syncthreads();
  if (lane < 13) {
    float sum = 0.0f;
    if (lane < 10) {
      const float* Wr = W_ro_s + layer * CC * NEL;
      for (int dd = 0; dd < CC; ++dd) sum = fmaf(lf[w][dd][0], Wr[dd * NEL + lane], sum);
    } else {
      int mm = lane - 10;
      const float* Wv = W_ro_v + layer * CC;
      for (int dd = 0; dd < CC; ++dd) sum = fmaf(lf[w][dd][1 + mm], Wv[dd], sum);
    }
    pred[n * 13 + lane] += sum;
  }
}

// ---------------- K7: loss accumulation (hierarchical: LDS -> global) --------
__global__ __launch_bounds__(256) void k_loss(const float* __restrict__ pred,
    const float* __restrict__ eps, const int* __restrict__ batch,
    float* __restrict__ lnum, float* __restrict__ lcnt)
{
  __shared__ float psum[GG];
  __shared__ int pcnt[GG];
  int tid = threadIdx.x;
  if (tid < GG) { psum[tid] = 0.0f; pcnt[tid] = 0; }
  __syncthreads();
  int n = blockIdx.x * 256 + tid;
  if (n < NN) {
    int g = batch[n];
    float sum = 0.0f;
#pragma unroll
    for (int j = 0; j < 13; ++j) {
      float dlt = pred[n * 13 + j] - eps[n * 13 + j];
      sum = fmaf(dlt, dlt, sum);
    }
    atomicAdd(&psum[g], sum);   // LDS atomic; batch sorted -> 1-2 distinct g per block
    atomicAdd(&pcnt[g], 1);
  }
  __syncthreads();
  if (tid < GG && pcnt[tid] > 0) {
    atomicAdd(&lnum[tid], psum[tid]);
    atomicAdd(&lcnt[tid], (float)pcnt[tid]);
  }
}

__global__ void k_final(const float* __restrict__ lnum, const float* __restrict__ lcnt,
    float* __restrict__ out)
{
  int g = threadIdx.x;
  if (g < GG) {
    float nn = fmaxf(lcnt[g], 1.0f);
    out[g] = 0.5f * lnum[g] / (nn * 13.0f);
  }
}

extern "C" void kernel_launch(void* const* d_in, const int* in_sizes, int n_in,
                              void* d_out, int out_size, void* d_ws, size_t ws_size,
                              hipStream_t stream) {
  const float* positions  = (const float*)d_in[0];
  const float* node_attrs = (const float*)d_in[1];
  const float* shifts     = (const float*)d_in[2];
  const float* eps        = (const float*)d_in[3];
  const float* alpha_bar  = (const float*)d_in[4];
  const float* W_embed    = (const float*)d_in[5];
  const float* W_r1       = (const float*)d_in[6];
  const float* W_r2       = (const float*)d_in[7];
  const float* W_mix      = (const float*)d_in[8];
  const float* W_sc       = (const float*)d_in[9];
  const float* W_prod     = (const float*)d_in[10];
  const float* W_ro_s     = (const float*)d_in[11];
  const float* W_ro_v     = (const float*)d_in[12];
  const int* edge_index   = (const int*)d_in[13];
  const int* batch        = (const int*)d_in[14];
  const int* tarr         = (const int*)d_in[15];
  float* out = (float*)d_out;

  char* ws = (char*)d_ws;
  size_t off = 0;
  auto alloc = [&](size_t bytes) -> void* {
    void* p = ws + off;
    off = (off + bytes + 255) & ~(size_t)255;
    return p;
  };
  // total ~107 MB (ws_size = 256 MiB per round-5 fillBuffer evidence)
  float* pos_noisy = (float*)alloc(NN * 3 * 4);
  float* scalA     = (float*)alloc(NN * CC * 4);
  float* scalB     = (float*)alloc(NN * CC * 4);
  float* sc_skip   = (float*)alloc(NN * CC * 4);
  float* pred      = (float*)alloc(NN * 13 * 4);
  ushort_t* Ys     = (ushort_t*)alloc((size_t)EE * 16 * 2);  // sorted, bf16
  ushort_t* efs    = (ushort_t*)alloc((size_t)EE * 8 * 2);   // sorted, bf16
  int* snds        = (int*)alloc((size_t)EE * 4);            // sorted sender ids
  ushort_t* rwc    = (ushort_t*)alloc((size_t)EE * 128 * 2); // rw*ss, bf16 (82 MB)
  int* deg         = (int*)alloc(NN * 4);
  int* offs        = (int*)alloc((NN + 1) * 4);
  int* cursor      = (int*)alloc(NN * 4);
  float* lnum      = (float*)alloc(GG * 4);
  float* lcnt      = (float*)alloc(GG * 4);
  (void)ws_size; (void)in_sizes; (void)n_in; (void)out_size;

  const int NB_N = (NN + 255) / 256;   // 79
  const int NB_E = EE / 256;           // 1250

  k_prep<<<NB_N, 256, 0, stream>>>(positions, node_attrs, eps, alpha_bar, W_embed,
                                   W_sc, batch, tarr, pos_noisy, scalA, sc_skip, pred, deg);
  k_edge_deg<<<NB_E, 256, 0, stream>>>(edge_index, deg);
  k_scan<<<1, 1024, 0, stream>>>(deg, offs, cursor, lnum, lcnt);
  k_edge2<<<NB_E, 256, 0, stream>>>(pos_noisy, shifts, edge_index, cursor, Ys, efs, snds);

  for (int layer = 0; layer < 2; ++layer) {
    const float* sin_p = (layer == 0) ? scalA : scalB;
    float* sout_p      = (layer == 0) ? scalB : scalA;
    k_rw_mfma<<<NB_E, 256, 0, stream>>>(efs, W_r1, W_r2, snds, sin_p, rwc, layer);
    k_layer<<<NN / 4, 256, 0, stream>>>(Ys, rwc, sout_p, offs,
                                        W_mix, W_prod, W_ro_s, W_ro_v,
                                        sc_skip, pred, layer);
  }

  k_loss<<<NB_N, 256, 0, stream>>>(pred, eps, batch, lnum, lcnt);
  k_final<<<1, 64, 0, stream>>>(lnum, lcnt, out);
}